// Round 3
// baseline (149.529 us; speedup 1.0000x reference)
//
#include <hip/hip_runtime.h>
#include <hip/hip_bf16.h>

typedef __attribute__((ext_vector_type(4))) float f32x4;
typedef __attribute__((ext_vector_type(8))) short bf16x8;

static __device__ __forceinline__ unsigned short f2bf(float f) {
  union { float f; unsigned u; } v;
  v.f = f;
  unsigned r = v.u + 0x7FFFu + ((v.u >> 16) & 1u);
  return (unsigned short)(r >> 16);
}

static __device__ __forceinline__ void gload16(const void* g, void* lds) {
  __builtin_amdgcn_global_load_lds(
      (const __attribute__((address_space(1))) unsigned int*)g,
      (__attribute__((address_space(3))) unsigned int*)lds, 16, 0, 0);
}

// ---------------- cast f32 -> bf16, vectorized ----------------
__global__ __launch_bounds__(256) void cast_bf16_kernel(
    const float* __restrict__ in, unsigned short* __restrict__ out) {
  int i = blockIdx.x * 256 + threadIdx.x;
  float4 v = reinterpret_cast<const float4*>(in)[i];
  ushort4 o;
  o.x = f2bf(v.x); o.y = f2bf(v.y); o.z = f2bf(v.z); o.w = f2bf(v.w);
  reinterpret_cast<ushort4*>(out)[i] = o;
}

// ---------------- transpose + cast: [R][C] f32 -> [C][R] bf16 ----------------
__global__ __launch_bounds__(256) void transpose_cast_kernel(
    const float* __restrict__ in, unsigned short* __restrict__ out, int R, int C) {
  __shared__ float tile[32][33];
  int c0 = blockIdx.x * 32, r0 = blockIdx.y * 32;
  int tx = threadIdx.x & 31, ty = threadIdx.x >> 5;  // ty 0..7
#pragma unroll
  for (int i = 0; i < 32; i += 8)
    tile[ty + i][tx] = in[(size_t)(r0 + ty + i) * C + c0 + tx];
  __syncthreads();
#pragma unroll
  for (int i = 0; i < 32; i += 8)
    out[(size_t)(c0 + ty + i) * R + r0 + tx] = f2bf(tile[tx][ty + i]);
}

// ---------------- bf16 GEMM, 128x128 tile, BK=32, 4 waves ----------------
template <int MODE>
__global__ __launch_bounds__(256) void gemm_bf16(
    const unsigned short* __restrict__ A,
    const unsigned short* __restrict__ Bt,
    const float* __restrict__ bias,
    unsigned short* __restrict__ q_out,
    unsigned short* __restrict__ k_out,
    unsigned short* __restrict__ v_out,
    float* __restrict__ f_out) {
  __shared__ __align__(16) unsigned short As[128 * 32];
  __shared__ __align__(16) unsigned short Bs[128 * 32];

  const int tid = threadIdx.x;
  const int wid = tid >> 6, lane = tid & 63;
  const int l15 = lane & 15, g = lane >> 4;
  const int wm = wid >> 1, wn = wid & 1;
  const int n0 = blockIdx.x * 128, m0 = blockIdx.y * 128;

  f32x4 acc[4][4] = {};

  for (int k0 = 0; k0 < 1024; k0 += 32) {
    __syncthreads();
#pragma unroll
    for (int i = 0; i < 2; ++i) {
      int t = tid + i * 256;
      int row = t >> 2;
      int c8 = (t & 3) << 3;
      gload16(A + (size_t)(m0 + row) * 1024 + k0 + c8, As + (i * 256 + wid * 64) * 8);
      gload16(Bt + (size_t)(n0 + row) * 1024 + k0 + c8, Bs + (i * 256 + wid * 64) * 8);
    }
    __syncthreads();
    bf16x8 a[4], b[4];
#pragma unroll
    for (int mi = 0; mi < 4; ++mi)
      a[mi] = *reinterpret_cast<const bf16x8*>(As + (wm * 64 + mi * 16 + l15) * 32 + g * 8);
#pragma unroll
    for (int ni = 0; ni < 4; ++ni)
      b[ni] = *reinterpret_cast<const bf16x8*>(Bs + (wn * 64 + ni * 16 + l15) * 32 + g * 8);
#pragma unroll
    for (int mi = 0; mi < 4; ++mi)
#pragma unroll
      for (int ni = 0; ni < 4; ++ni)
        acc[mi][ni] = __builtin_amdgcn_mfma_f32_16x16x32_bf16(a[mi], b[ni], acc[mi][ni], 0, 0, 0);
  }

  if (MODE == 0) {
    const int which = n0 >> 10;  // block-uniform: 128 | 1024
    unsigned short* dst = (which == 0) ? q_out : (which == 1) ? k_out : v_out;
#pragma unroll
    for (int ni = 0; ni < 4; ++ni) {
      int col = n0 + wn * 64 + ni * 16 + l15;
      int c = col & 1023;
      int h = c >> 6, d = c & 63;
      float bv = bias[col];
#pragma unroll
      for (int mi = 0; mi < 4; ++mi) {
#pragma unroll
        for (int r = 0; r < 4; ++r) {
          int rowg = m0 + wm * 64 + mi * 16 + g * 4 + r;
          int bb = rowg >> 11, tt = rowg & 2047;
          dst[((bb * 16 + h) * 2048 + tt) * 64 + d] = f2bf(acc[mi][ni][r] + bv);
        }
      }
    }
  } else {
#pragma unroll
    for (int ni = 0; ni < 4; ++ni) {
      int col = n0 + wn * 64 + ni * 16 + l15;
      float bv = bias[col];
#pragma unroll
      for (int mi = 0; mi < 4; ++mi)
#pragma unroll
        for (int r = 0; r < 4; ++r) {
          int rowg = m0 + wm * 64 + mi * 16 + g * 4 + r;
          f_out[(size_t)rowg * 1024 + col] = acc[mi][ni][r] + bv;
        }
    }
  }
}

// ---------------- causal flash attention: K in registers ----------------
// Q,K,V: [BH=32][T=2048][D=64] bf16. O: [B*T=4096][C=1024] bf16.
// grid (16, 32): block handles q-tiles {pi, 31-pi} -> 33 KV-tiles, balanced.
// K-tile A-fragments loaded global->VGPR (double-buffered); no K LDS staging.
#define VT_SZ (64 * 72)

__device__ __forceinline__ void write_vt(unsigned short* VtBuf, int kvL, int d8,
                                         bf16x8 va, bf16x8 vb) {
#pragma unroll
  for (int j = 0; j < 8; ++j) {
    unsigned pk = (unsigned)(unsigned short)va[j] |
                  ((unsigned)(unsigned short)vb[j] << 16);
    *reinterpret_cast<unsigned*>(&VtBuf[(d8 + j) * 72 + kvL]) = pk;
  }
}

__device__ __forceinline__ void attn_run_qtile(
    const unsigned short* __restrict__ Qb,
    const unsigned short* __restrict__ Kb,
    const unsigned short* __restrict__ Vb,
    unsigned short* __restrict__ O,
    int b, int h, int q0, int nt,
    unsigned short* Vt, unsigned short* Ps,
    int tid, int wid, int l15, int g) {
  const float SC = 0.125f * 1.44269504f;  // scale * log2(e); softmax in exp2 space

  bf16x8 qf[2];
  {
    const unsigned short* qrow = Qb + (size_t)(q0 + wid * 16 + l15) * 64;
    qf[0] = *reinterpret_cast<const bf16x8*>(qrow + g * 8);
    qf[1] = *reinterpret_cast<const bf16x8*>(qrow + 32 + g * 8);
  }

  // per-lane K fragment base: row = l15 (+k0+mi*16), d = g*8 (+kk*32)
  const unsigned short* Kl = Kb + (size_t)l15 * 64 + g * 8;

  float m_run = -1e30f, l_run = 0.0f;
  f32x4 ot[4] = {};
  const int qg = q0 + wid * 16 + l15;
  const int kvL = (tid & 31) * 2, d8 = (tid >> 5) * 8;
  const int qrow = wid * 16 + l15;

  bf16x8 kc[2][4], kn[2][4];

  // prologue: K(0) frags -> regs, V(0) -> Vt buffer 0
#pragma unroll
  for (int kk = 0; kk < 2; ++kk)
#pragma unroll
    for (int mi = 0; mi < 4; ++mi)
      kc[kk][mi] = *reinterpret_cast<const bf16x8*>(Kl + (size_t)(mi * 16) * 64 + kk * 32);
  {
    const unsigned short* vp = Vb + (size_t)kvL * 64 + d8;
    bf16x8 va = *reinterpret_cast<const bf16x8*>(vp);
    bf16x8 vb = *reinterpret_cast<const bf16x8*>(vp + 64);
    write_vt(Vt, kvL, d8, va, vb);
  }
  __syncthreads();

  for (int t = 0; t < nt; ++t) {
    const unsigned short* VtC = Vt + (t & 1) * VT_SZ;
    bf16x8 va, vb;
    const bool pf = (t + 1 < nt);
    if (pf) {
      // issue next tile's K/V reg loads early; consumed at iteration end (T14)
      const unsigned short* vp = Vb + (size_t)(((t + 1) << 6) + kvL) * 64 + d8;
      va = *reinterpret_cast<const bf16x8*>(vp);
      vb = *reinterpret_cast<const bf16x8*>(vp + 64);
      const unsigned short* kp = Kl + ((size_t)(t + 1) << 12);
#pragma unroll
      for (int kk = 0; kk < 2; ++kk)
#pragma unroll
        for (int mi = 0; mi < 4; ++mi)
          kn[kk][mi] = *reinterpret_cast<const bf16x8*>(kp + (size_t)(mi * 16) * 64 + kk * 32);
    }

    // S^T = K · Q^T — pure-register MFMA, no LDS dependency
    f32x4 s[4] = {};
    __builtin_amdgcn_s_setprio(1);
#pragma unroll
    for (int kk = 0; kk < 2; ++kk)
#pragma unroll
      for (int mi = 0; mi < 4; ++mi)
        s[mi] = __builtin_amdgcn_mfma_f32_16x16x32_bf16(kc[kk][mi], qf[kk], s[mi], 0, 0, 0);
    __builtin_amdgcn_s_setprio(0);

    // scale (+ causal mask on diagonal tile only), tree row-max
    if (t == nt - 1) {
      const int k0 = t << 6;
#pragma unroll
      for (int mi = 0; mi < 4; ++mi)
#pragma unroll
        for (int r = 0; r < 4; ++r) {
          int kvg = k0 + mi * 16 + g * 4 + r;
          float sv = s[mi][r] * SC;
          s[mi][r] = (kvg <= qg) ? sv : -1e30f;
        }
    } else {
#pragma unroll
      for (int mi = 0; mi < 4; ++mi)
#pragma unroll
        for (int r = 0; r < 4; ++r) s[mi][r] *= SC;
    }
    float mx[4];
#pragma unroll
    for (int mi = 0; mi < 4; ++mi)
      mx[mi] = fmaxf(fmaxf(s[mi][0], s[mi][1]), fmaxf(s[mi][2], s[mi][3]));
    float tmax = fmaxf(fmaxf(mx[0], mx[1]), fmaxf(mx[2], mx[3]));
    tmax = fmaxf(tmax, __shfl_xor(tmax, 16));
    tmax = fmaxf(tmax, __shfl_xor(tmax, 32));

    // defer-max (T13): skip O-rescale while max grows < 8 (exp2 units)
    if (!__all(tmax <= m_run + 8.0f)) {
      float m_new = fmaxf(m_run, tmax);
      float corr = __builtin_amdgcn_exp2f(m_run - m_new);
      l_run *= corr;
#pragma unroll
      for (int mi = 0; mi < 4; ++mi)
#pragma unroll
        for (int r = 0; r < 4; ++r) ot[mi][r] *= corr;
      m_run = m_new;
    }

    float tsum = 0.f;
#pragma unroll
    for (int mi = 0; mi < 4; ++mi) {
#pragma unroll
      for (int r2 = 0; r2 < 2; ++r2) {
        float p0 = __builtin_amdgcn_exp2f(s[mi][2 * r2] - m_run);
        float p1 = __builtin_amdgcn_exp2f(s[mi][2 * r2 + 1] - m_run);
        tsum += p0 + p1;
        unsigned pk = (unsigned)f2bf(p0) | ((unsigned)f2bf(p1) << 16);
        *reinterpret_cast<unsigned*>(&Ps[qrow * 72 + mi * 16 + g * 4 + 2 * r2]) = pk;
      }
    }
    tsum += __shfl_xor(tsum, 16);
    tsum += __shfl_xor(tsum, 32);
    l_run += tsum;

    // O^T += V^T · P^T
    __builtin_amdgcn_s_setprio(1);
#pragma unroll
    for (int kk = 0; kk < 2; ++kk) {
      bf16x8 pfr = *reinterpret_cast<const bf16x8*>(Ps + qrow * 72 + kk * 32 + g * 8);
#pragma unroll
      for (int mi = 0; mi < 4; ++mi) {
        bf16x8 vf = *reinterpret_cast<const bf16x8*>(VtC + (mi * 16 + l15) * 72 + kk * 32 + g * 8);
        ot[mi] = __builtin_amdgcn_mfma_f32_16x16x32_bf16(vf, pfr, ot[mi], 0, 0, 0);
      }
    }
    __builtin_amdgcn_s_setprio(0);

    if (pf) {
      write_vt(Vt + ((t + 1) & 1) * VT_SZ, kvL, d8, va, vb);
#pragma unroll
      for (int kk = 0; kk < 2; ++kk)
#pragma unroll
        for (int mi = 0; mi < 4; ++mi) kc[kk][mi] = kn[kk][mi];
    }
    __syncthreads();
  }

  // epilogue: O^T -> LDS scratch (Vt buf 0, swizzled) -> coalesced stores
  unsigned short* scr = Vt;
  float inv_l = 1.0f / l_run;
#pragma unroll
  for (int mi = 0; mi < 4; ++mi)
#pragma unroll
    for (int r = 0; r < 4; ++r) {
      int d = mi * 16 + g * 4 + r;
      int cb = (d * 2) ^ ((qrow & 7) << 4);
      *reinterpret_cast<unsigned short*>((char*)scr + qrow * 128 + cb) =
          f2bf(ot[mi][r] * inv_l);
    }
  __syncthreads();
#pragma unroll
  for (int i = 0; i < 2; ++i) {
    int t = tid + i * 256;
    int row = t >> 3;
    int cb = (t & 7) << 4;
    int sw = cb ^ ((row & 7) << 4);
    bf16x8 vv = *reinterpret_cast<const bf16x8*>((const char*)scr + row * 128 + sw);
    *reinterpret_cast<bf16x8*>(O + ((size_t)(b * 2048 + q0 + row)) * 1024 + h * 64 + (cb >> 1)) = vv;
  }
  __syncthreads();  // protect scratch before next q-tile's prologue
}

__global__ __launch_bounds__(256) void attn_fwd(
    const unsigned short* __restrict__ Q,
    const unsigned short* __restrict__ K,
    const unsigned short* __restrict__ V,
    unsigned short* __restrict__ O) {
  __shared__ __align__(16) unsigned short Vt[2 * VT_SZ];  // 18 KB, V^T stride 72
  __shared__ __align__(16) unsigned short Ps[64 * 72];    // 9 KB

  const int tid = threadIdx.x;
  const int wid = tid >> 6;
  const int l15 = tid & 15;
  const int g = (tid & 63) >> 4;

  // bijective XCD swizzle (T1): all 16 q-tile blocks of one bh on one XCD
  int lin = blockIdx.x + (blockIdx.y << 4);
  int w = ((lin & 7) << 6) + (lin >> 3);
  const int pi = w & 15, bh = w >> 4;
  const int b = bh >> 4, h = bh & 15;

  const unsigned short* Qb = Q + (size_t)bh * 2048 * 64;
  const unsigned short* Kb = K + (size_t)bh * 2048 * 64;
  const unsigned short* Vb = V + (size_t)bh * 2048 * 64;

  // q-tile A = pi (pi+1 KV tiles), q-tile B = 31-pi (32-pi KV tiles): 33 total
  attn_run_qtile(Qb, Kb, Vb, O, b, h, pi << 6, pi + 1, Vt, Ps, tid, wid, l15, g);
  attn_run_qtile(Qb, Kb, Vb, O, b, h, (31 - pi) << 6, 32 - pi, Vt, Ps, tid, wid, l15, g);
}

// ---------------- launch ----------------
extern "C" void kernel_launch(void* const* d_in, const int* in_sizes, int n_in,
                              void* d_out, int out_size, void* d_ws, size_t ws_size,
                              hipStream_t stream) {
  const float* x = (const float*)d_in[0];
  const float* w_qkv = (const float*)d_in[1];
  const float* b_qkv = (const float*)d_in[2];
  const float* w_out = (const float*)d_in[3];
  const float* b_out = (const float*)d_in[4];
  float* out = (float*)d_out;
  char* ws = (char*)d_ws;

  unsigned short* xb    = (unsigned short*)d_out;            // dead before GEMM2 writes
  unsigned short* wqkvT = (unsigned short*)(ws);             //  6 MB
  unsigned short* woT   = (unsigned short*)(ws + 6291456);   //  2 MB
  unsigned short* q_buf = (unsigned short*)(ws + 8388608);   //  8 MB
  unsigned short* k_buf = (unsigned short*)(ws + 16777216);  //  8 MB
  unsigned short* v_buf = (unsigned short*)(ws + 25165824);  //  8 MB
  unsigned short* aout  = (unsigned short*)(ws + 33554432);  //  8 MB -> 40 MB total

  cast_bf16_kernel<<<dim3(4096), dim3(256), 0, stream>>>(x, xb);
  transpose_cast_kernel<<<dim3(96, 32), dim3(256), 0, stream>>>(w_qkv, wqkvT, 1024, 3072);
  transpose_cast_kernel<<<dim3(32, 32), dim3(256), 0, stream>>>(w_out, woT, 1024, 1024);

  gemm_bf16<0><<<dim3(24, 32), dim3(256), 0, stream>>>(
      xb, wqkvT, b_qkv, q_buf, k_buf, v_buf, nullptr);

  attn_fwd<<<dim3(16, 32), dim3(256), 0, stream>>>(q_buf, k_buf, v_buf, aout);

  gemm_bf16<1><<<dim3(8, 32), dim3(256), 0, stream>>>(
      aout, woT, b_out, nullptr, nullptr, nullptr, out);
}

// Round 4
// 121.091 us; speedup vs baseline: 1.2349x; 1.2349x over previous
//
#include <hip/hip_runtime.h>
#include <hip/hip_bf16.h>

typedef __attribute__((ext_vector_type(4))) float f32x4;
typedef __attribute__((ext_vector_type(8))) short bf16x8;

static __device__ __forceinline__ unsigned short f2bf(float f) {
  union { float f; unsigned u; } v;
  v.f = f;
  unsigned r = v.u + 0x7FFFu + ((v.u >> 16) & 1u);
  return (unsigned short)(r >> 16);
}

static __device__ __forceinline__ void gload16(const void* g, void* lds) {
  __builtin_amdgcn_global_load_lds(
      (const __attribute__((address_space(1))) unsigned int*)g,
      (__attribute__((address_space(3))) unsigned int*)lds, 16, 0, 0);
}

// ---------------- fused prep: cast x, transpose+cast w_qkv / w_out ----------------
__global__ __launch_bounds__(256) void prep_kernel(
    const float* __restrict__ x, const float* __restrict__ w_qkv,
    const float* __restrict__ w_out, unsigned short* __restrict__ xb,
    unsigned short* __restrict__ wqkvT, unsigned short* __restrict__ woT) {
  __shared__ float tile[32][33];
  const int bid = blockIdx.x, tid = threadIdx.x;
  if (bid < 4096) {  // cast x -> bf16
    int i = bid * 256 + tid;
    float4 v = reinterpret_cast<const float4*>(x)[i];
    ushort4 o;
    o.x = f2bf(v.x); o.y = f2bf(v.y); o.z = f2bf(v.z); o.w = f2bf(v.w);
    reinterpret_cast<ushort4*>(xb)[i] = o;
    return;
  }
  const float* src; unsigned short* dst; int c0, r0, C;
  if (bid < 7168) {  // w_qkv [1024][3072] -> wqkvT [3072][1024]
    int t = bid - 4096;
    src = w_qkv; dst = wqkvT; C = 3072;
    c0 = (t % 96) * 32; r0 = (t / 96) * 32;
  } else {           // w_out [1024][1024] -> woT [1024][1024]
    int t = bid - 7168;
    src = w_out; dst = woT; C = 1024;
    c0 = (t & 31) * 32; r0 = (t >> 5) * 32;
  }
  int tx = tid & 31, ty = tid >> 5;  // ty 0..7
#pragma unroll
  for (int i = 0; i < 32; i += 8)
    tile[ty + i][tx] = src[(size_t)(r0 + ty + i) * C + c0 + tx];
  __syncthreads();
#pragma unroll
  for (int i = 0; i < 32; i += 8)
    dst[(size_t)(c0 + ty + i) * 1024 + r0 + tx] = f2bf(tile[tx][ty + i]);
}

// ---------------- bf16 GEMM, 128xBN tile, BK=32, 2-phase prefetch ----------------
// A: [M][1024] bf16. Bt: [N][1024] bf16 (B^T). bias: f32 [N].
// MODE 0 (BN=128): scatter epilogue -> Q/K/V [BH][2048][64] bf16
// MODE 1 (BN=64):  f32 epilogue -> f_out [M][1024]
template <int MODE, int BN>
__global__ __launch_bounds__(256) void gemm_bf16(
    const unsigned short* __restrict__ A,
    const unsigned short* __restrict__ Bt,
    const float* __restrict__ bias,
    unsigned short* __restrict__ q_out,
    unsigned short* __restrict__ k_out,
    unsigned short* __restrict__ v_out,
    float* __restrict__ f_out) {
  constexpr int NB2 = BN / 32;      // B-frags / acc cols per wave
  constexpr int NBL = BN / 64;      // B stage loads per thread
  __shared__ __align__(16) unsigned short As[2][128 * 32];
  __shared__ __align__(16) unsigned short Bs[2][BN * 32];

  const int tid = threadIdx.x;
  const int wid = tid >> 6, lane = tid & 63;
  const int l15 = lane & 15, g = lane >> 4;
  const int wm = wid >> 1, wn = wid & 1;
  const int n0 = blockIdx.x * BN, m0 = blockIdx.y * 128;

  f32x4 acc[4][NB2] = {};

  auto stage = [&](int k0, int bsel) {
#pragma unroll
    for (int i = 0; i < 2; ++i) {
      int t = tid + i * 256;
      int row = t >> 2, c8 = (t & 3) << 3;
      gload16(A + (size_t)(m0 + row) * 1024 + k0 + c8, &As[bsel][(i * 256 + wid * 64) * 8]);
    }
#pragma unroll
    for (int i = 0; i < NBL; ++i) {
      int t = tid + i * 256;
      int row = t >> 2, c8 = (t & 3) << 3;
      gload16(Bt + (size_t)(n0 + row) * 1024 + k0 + c8, &Bs[bsel][(i * 256 + wid * 64) * 8]);
    }
  };

  stage(0, 0);
  __syncthreads();
  for (int ks = 0; ks < 32; ++ks) {
    const int cur = ks & 1;
    if (ks + 1 < 32) stage((ks + 1) * 32, cur ^ 1);  // lands under MFMA (T3-lite)
    bf16x8 a[4], b[NB2];
#pragma unroll
    for (int mi = 0; mi < 4; ++mi)
      a[mi] = *reinterpret_cast<const bf16x8*>(&As[cur][(wm * 64 + mi * 16 + l15) * 32 + g * 8]);
#pragma unroll
    for (int ni = 0; ni < NB2; ++ni)
      b[ni] = *reinterpret_cast<const bf16x8*>(&Bs[cur][(wn * (BN / 2) + ni * 16 + l15) * 32 + g * 8]);
    __builtin_amdgcn_s_setprio(1);
#pragma unroll
    for (int mi = 0; mi < 4; ++mi)
#pragma unroll
      for (int ni = 0; ni < NB2; ++ni)
        acc[mi][ni] = __builtin_amdgcn_mfma_f32_16x16x32_bf16(a[mi], b[ni], acc[mi][ni], 0, 0, 0);
    __builtin_amdgcn_s_setprio(0);
    __syncthreads();  // drains vmcnt for the prefetch (covered by MFMA above)
  }

  if (MODE == 0) {
    const int which = n0 >> 10;  // block-uniform
    unsigned short* dst = (which == 0) ? q_out : (which == 1) ? k_out : v_out;
#pragma unroll
    for (int ni = 0; ni < NB2; ++ni) {
      int col = n0 + wn * (BN / 2) + ni * 16 + l15;
      int c = col & 1023;
      int h = c >> 6, d = c & 63;
      float bv = bias[col];
#pragma unroll
      for (int mi = 0; mi < 4; ++mi) {
#pragma unroll
        for (int r = 0; r < 4; ++r) {
          int rowg = m0 + wm * 64 + mi * 16 + g * 4 + r;
          int bb = rowg >> 11, tt = rowg & 2047;
          dst[((bb * 16 + h) * 2048 + tt) * 64 + d] = f2bf(acc[mi][ni][r] + bv);
        }
      }
    }
  } else {
#pragma unroll
    for (int ni = 0; ni < NB2; ++ni) {
      int col = n0 + wn * (BN / 2) + ni * 16 + l15;
      float bv = bias[col];
#pragma unroll
      for (int mi = 0; mi < 4; ++mi)
#pragma unroll
        for (int r = 0; r < 4; ++r) {
          int rowg = m0 + wm * 64 + mi * 16 + g * 4 + r;
          f_out[(size_t)rowg * 1024 + col] = acc[mi][ni][r] + bv;
        }
    }
  }
}

// ---------------- causal flash attention (round-2 proven structure) ----------------
// Q,K,V: [BH=32][T=2048][D=64] bf16. O: [B*T=4096][C=1024] bf16.
// grid (16, 32): block handles q-tiles {pi, 31-pi} -> 33 KV-tiles each, balanced.
#define KS_SZ (64 * 64)
#define VT_SZ (64 * 72)

__device__ __forceinline__ void attn_stage_K(const unsigned short* __restrict__ Kb,
                                             int k0, unsigned short* KsBuf,
                                             int tid, int wid) {
#pragma unroll
  for (int i = 0; i < 2; ++i) {
    int t = tid + i * 256;
    int row = t >> 3;
    int cb = (t & 7) << 4;
    int src = cb ^ ((row & 7) << 4);  // pre-swizzled global source (rule 21)
    gload16((const char*)Kb + (size_t)(k0 + row) * 128 + src,
            (char*)KsBuf + (i * 256 + wid * 64) * 16);
  }
}

__device__ __forceinline__ void write_vt(unsigned short* VtBuf, int kvL, int d8,
                                         bf16x8 va, bf16x8 vb) {
#pragma unroll
  for (int j = 0; j < 8; ++j) {
    unsigned pk = (unsigned)(unsigned short)va[j] |
                  ((unsigned)(unsigned short)vb[j] << 16);
    *reinterpret_cast<unsigned*>(&VtBuf[(d8 + j) * 72 + kvL]) = pk;
  }
}

__device__ __forceinline__ void attn_run_qtile(
    const unsigned short* __restrict__ Qb,
    const unsigned short* __restrict__ Kb,
    const unsigned short* __restrict__ Vb,
    unsigned short* __restrict__ O,
    int b, int h, int q0, int nt,
    unsigned short* Ks, unsigned short* Vt, unsigned short* Ps,
    int tid, int wid, int l15, int g) {
  const float SC = 0.125f * 1.44269504f;  // scale * log2(e); softmax in exp2 space

  bf16x8 qf[2];
  {
    const unsigned short* qrow = Qb + (size_t)(q0 + wid * 16 + l15) * 64;
    qf[0] = *reinterpret_cast<const bf16x8*>(qrow + g * 8);
    qf[1] = *reinterpret_cast<const bf16x8*>(qrow + 32 + g * 8);
  }

  float m_run = -1e30f, l_run = 0.0f;
  f32x4 ot[4] = {};
  const int qg = q0 + wid * 16 + l15;
  const int kvL = (tid & 31) * 2, d8 = (tid >> 5) * 8;
  const int qrow = wid * 16 + l15;

  // prologue: stage tile 0 into buffer 0
  attn_stage_K(Kb, 0, Ks, tid, wid);
  {
    const unsigned short* vp = Vb + (size_t)kvL * 64 + d8;
    bf16x8 va = *reinterpret_cast<const bf16x8*>(vp);
    bf16x8 vb = *reinterpret_cast<const bf16x8*>(vp + 64);
    write_vt(Vt, kvL, d8, va, vb);
  }
  __syncthreads();

  for (int t = 0; t < nt; ++t) {
    const unsigned short* KsC = Ks + (t & 1) * KS_SZ;
    const unsigned short* VtC = Vt + (t & 1) * VT_SZ;
    bf16x8 va, vb;
    const bool pf = (t + 1 < nt);
    if (pf) {
      // issue next tile's loads early; they land during compute (T14)
      attn_stage_K(Kb, (t + 1) << 6, Ks + ((t + 1) & 1) * KS_SZ, tid, wid);
      const unsigned short* vp = Vb + (size_t)(((t + 1) << 6) + kvL) * 64 + d8;
      va = *reinterpret_cast<const bf16x8*>(vp);
      vb = *reinterpret_cast<const bf16x8*>(vp + 64);
    }

    // S^T = K · Q^T
    f32x4 s[4] = {};
    __builtin_amdgcn_s_setprio(1);
#pragma unroll
    for (int kk = 0; kk < 2; ++kk)
#pragma unroll
      for (int mi = 0; mi < 4; ++mi) {
        int row = mi * 16 + l15;
        int cb = (kk * 64 + g * 16) ^ ((row & 7) << 4);
        bf16x8 kf = *reinterpret_cast<const bf16x8*>((const char*)KsC + row * 128 + cb);
        s[mi] = __builtin_amdgcn_mfma_f32_16x16x32_bf16(kf, qf[kk], s[mi], 0, 0, 0);
      }
    __builtin_amdgcn_s_setprio(0);

    // scale (+ causal mask on the diagonal tile only) and row max
    float tmax = -1e30f;
    if (t == nt - 1) {
      const int k0 = t << 6;
#pragma unroll
      for (int mi = 0; mi < 4; ++mi)
#pragma unroll
        for (int r = 0; r < 4; ++r) {
          int kvg = k0 + mi * 16 + g * 4 + r;
          float sv = s[mi][r] * SC;
          sv = (kvg <= qg) ? sv : -1e30f;
          s[mi][r] = sv;
          tmax = fmaxf(tmax, sv);
        }
    } else {
#pragma unroll
      for (int mi = 0; mi < 4; ++mi)
#pragma unroll
        for (int r = 0; r < 4; ++r) {
          float sv = s[mi][r] * SC;
          s[mi][r] = sv;
          tmax = fmaxf(tmax, sv);
        }
    }
    tmax = fmaxf(tmax, __shfl_xor(tmax, 16));
    tmax = fmaxf(tmax, __shfl_xor(tmax, 32));

    // defer-max (T13): skip O-rescale while max grows < 8 (exp2 units)
    if (!__all(tmax <= m_run + 8.0f)) {
      float m_new = fmaxf(m_run, tmax);
      float corr = __builtin_amdgcn_exp2f(m_run - m_new);
      l_run *= corr;
#pragma unroll
      for (int mi = 0; mi < 4; ++mi)
#pragma unroll
        for (int r = 0; r < 4; ++r) ot[mi][r] *= corr;
      m_run = m_new;
    }

    float tsum = 0.f;
#pragma unroll
    for (int mi = 0; mi < 4; ++mi) {
#pragma unroll
      for (int r2 = 0; r2 < 2; ++r2) {
        float p0 = __builtin_amdgcn_exp2f(s[mi][2 * r2] - m_run);
        float p1 = __builtin_amdgcn_exp2f(s[mi][2 * r2 + 1] - m_run);
        tsum += p0 + p1;
        unsigned pk = (unsigned)f2bf(p0) | ((unsigned)f2bf(p1) << 16);
        *reinterpret_cast<unsigned*>(&Ps[qrow * 72 + mi * 16 + g * 4 + 2 * r2]) = pk;
      }
    }
    tsum += __shfl_xor(tsum, 16);
    tsum += __shfl_xor(tsum, 32);
    l_run += tsum;

    // O^T += V^T · P^T
    __builtin_amdgcn_s_setprio(1);
#pragma unroll
    for (int kk = 0; kk < 2; ++kk) {
      bf16x8 pfr = *reinterpret_cast<const bf16x8*>(Ps + qrow * 72 + kk * 32 + g * 8);
#pragma unroll
      for (int mi = 0; mi < 4; ++mi) {
        bf16x8 vf = *reinterpret_cast<const bf16x8*>(VtC + (mi * 16 + l15) * 72 + kk * 32 + g * 8);
        ot[mi] = __builtin_amdgcn_mfma_f32_16x16x32_bf16(vf, pfr, ot[mi], 0, 0, 0);
      }
    }
    __builtin_amdgcn_s_setprio(0);

    if (pf) write_vt(Vt + ((t + 1) & 1) * VT_SZ, kvL, d8, va, vb);
    __syncthreads();  // drains prefetch vmcnt (hidden under compute) + buffer handoff
  }

  // epilogue: O^T -> LDS (reuse Ks, swizzled) -> coalesced stores
  float inv_l = 1.0f / l_run;
#pragma unroll
  for (int mi = 0; mi < 4; ++mi)
#pragma unroll
    for (int r = 0; r < 4; ++r) {
      int d = mi * 16 + g * 4 + r;
      int cb = (d * 2) ^ ((qrow & 7) << 4);
      *reinterpret_cast<unsigned short*>((char*)Ks + qrow * 128 + cb) = f2bf(ot[mi][r] * inv_l);
    }
  __syncthreads();
#pragma unroll
  for (int i = 0; i < 2; ++i) {
    int t = tid + i * 256;
    int row = t >> 3;
    int cb = (t & 7) << 4;
    int sw = cb ^ ((row & 7) << 4);
    bf16x8 vv = *reinterpret_cast<const bf16x8*>((const char*)Ks + row * 128 + sw);
    *reinterpret_cast<bf16x8*>(O + ((size_t)(b * 2048 + q0 + row)) * 1024 + h * 64 + (cb >> 1)) = vv;
  }
  __syncthreads();  // protect Ks before next q-tile's staging
}

__global__ __launch_bounds__(256) void attn_fwd(
    const unsigned short* __restrict__ Q,
    const unsigned short* __restrict__ K,
    const unsigned short* __restrict__ V,
    unsigned short* __restrict__ O) {
  __shared__ __align__(16) unsigned short Ks[2 * KS_SZ];  // 16 KB, XOR-swizzled
  __shared__ __align__(16) unsigned short Vt[2 * VT_SZ];  // 18 KB, V^T stride 72
  __shared__ __align__(16) unsigned short Ps[64 * 72];    // 9 KB

  const int tid = threadIdx.x;
  const int wid = tid >> 6;
  const int l15 = tid & 15;
  const int g = (tid & 63) >> 4;

  // bijective XCD swizzle (T1): all 16 q-tile blocks of one bh on one XCD
  int lin = blockIdx.x + (blockIdx.y << 4);
  int w = ((lin & 7) << 6) + (lin >> 3);
  const int pi = w & 15, bh = w >> 4;
  const int b = bh >> 4, h = bh & 15;

  const unsigned short* Qb = Q + (size_t)bh * 2048 * 64;
  const unsigned short* Kb = K + (size_t)bh * 2048 * 64;
  const unsigned short* Vb = V + (size_t)bh * 2048 * 64;

  // q-tile A = pi (pi+1 KV tiles), q-tile B = 31-pi (32-pi KV tiles): 33 total
  attn_run_qtile(Qb, Kb, Vb, O, b, h, pi << 6, pi + 1, Ks, Vt, Ps, tid, wid, l15, g);
  attn_run_qtile(Qb, Kb, Vb, O, b, h, (31 - pi) << 6, 32 - pi, Ks, Vt, Ps, tid, wid, l15, g);
}

// ---------------- launch ----------------
extern "C" void kernel_launch(void* const* d_in, const int* in_sizes, int n_in,
                              void* d_out, int out_size, void* d_ws, size_t ws_size,
                              hipStream_t stream) {
  const float* x = (const float*)d_in[0];
  const float* w_qkv = (const float*)d_in[1];
  const float* b_qkv = (const float*)d_in[2];
  const float* w_out = (const float*)d_in[3];
  const float* b_out = (const float*)d_in[4];
  float* out = (float*)d_out;
  char* ws = (char*)d_ws;

  unsigned short* xb    = (unsigned short*)d_out;            // dead before GEMM2 writes
  unsigned short* wqkvT = (unsigned short*)(ws);             //  6 MB
  unsigned short* woT   = (unsigned short*)(ws + 6291456);   //  2 MB
  unsigned short* q_buf = (unsigned short*)(ws + 8388608);   //  8 MB
  unsigned short* k_buf = (unsigned short*)(ws + 16777216);  //  8 MB
  unsigned short* v_buf = (unsigned short*)(ws + 25165824);  //  8 MB
  unsigned short* aout  = (unsigned short*)(ws + 33554432);  //  8 MB -> 40 MB total

  prep_kernel<<<dim3(8192), dim3(256), 0, stream>>>(x, w_qkv, w_out, xb, wqkvT, woT);

  gemm_bf16<0, 128><<<dim3(24, 32), dim3(256), 0, stream>>>(
      xb, wqkvT, b_qkv, q_buf, k_buf, v_buf, nullptr);

  attn_fwd<<<dim3(16, 32), dim3(256), 0, stream>>>(q_buf, k_buf, v_buf, aout);

  gemm_bf16<1, 64><<<dim3(16, 32), dim3(256), 0, stream>>>(
      aout, woT, b_out, nullptr, nullptr, nullptr, out);
}

// Round 5
// 107.007 us; speedup vs baseline: 1.3974x; 1.1316x over previous
//
#include <hip/hip_runtime.h>
#include <hip/hip_bf16.h>

typedef __attribute__((ext_vector_type(4))) float f32x4;
typedef __attribute__((ext_vector_type(8))) short bf16x8;

static __device__ __forceinline__ unsigned short f2bf(float f) {
  union { float f; unsigned u; } v;
  v.f = f;
  unsigned r = v.u + 0x7FFFu + ((v.u >> 16) & 1u);
  return (unsigned short)(r >> 16);
}

static __device__ __forceinline__ unsigned cvt_pk_bf16(float lo, float hi) {
  unsigned r;
  asm("v_cvt_pk_bf16_f32 %0, %1, %2" : "=v"(r) : "v"(lo), "v"(hi));
  return r;
}

static __device__ __forceinline__ void gload16(const void* g, void* lds) {
  __builtin_amdgcn_global_load_lds(
      (const __attribute__((address_space(1))) unsigned int*)g,
      (__attribute__((address_space(3))) unsigned int*)lds, 16, 0, 0);
}

// ---------------- fused prep: cast x, transpose+cast w_qkv / w_out ----------------
__global__ __launch_bounds__(256) void prep_kernel(
    const float* __restrict__ x, const float* __restrict__ w_qkv,
    const float* __restrict__ w_out, unsigned short* __restrict__ xb,
    unsigned short* __restrict__ wqkvT, unsigned short* __restrict__ woT) {
  __shared__ float tile[32][33];
  const int bid = blockIdx.x, tid = threadIdx.x;
  if (bid < 4096) {  // cast x -> bf16
    int i = bid * 256 + tid;
    float4 v = reinterpret_cast<const float4*>(x)[i];
    ushort4 o;
    o.x = f2bf(v.x); o.y = f2bf(v.y); o.z = f2bf(v.z); o.w = f2bf(v.w);
    reinterpret_cast<ushort4*>(xb)[i] = o;
    return;
  }
  const float* src; unsigned short* dst; int c0, r0, C;
  if (bid < 7168) {  // w_qkv [1024][3072] -> wqkvT [3072][1024]
    int t = bid - 4096;
    src = w_qkv; dst = wqkvT; C = 3072;
    c0 = (t % 96) * 32; r0 = (t / 96) * 32;
  } else {           // w_out [1024][1024] -> woT [1024][1024]
    int t = bid - 7168;
    src = w_out; dst = woT; C = 1024;
    c0 = (t & 31) * 32; r0 = (t >> 5) * 32;
  }
  int tx = tid & 31, ty = tid >> 5;  // ty 0..7
#pragma unroll
  for (int i = 0; i < 32; i += 8)
    tile[ty + i][tx] = src[(size_t)(r0 + ty + i) * C + c0 + tx];
  __syncthreads();
#pragma unroll
  for (int i = 0; i < 32; i += 8)
    dst[(size_t)(c0 + ty + i) * 1024 + r0 + tx] = f2bf(tile[tx][ty + i]);
}

// ---------------- bf16 GEMM, 128xBN tile, BK=32, 2-phase prefetch ----------------
// MODE 0 (BN=128): scatter epilogue -> Q/K/V [BH][2048][64] bf16 (Q pre-scaled)
// MODE 1 (BN=64):  f32 epilogue -> f_out [M][1024]
template <int MODE, int BN>
__global__ __launch_bounds__(256, MODE == 0 ? 3 : 2) void gemm_bf16(
    const unsigned short* __restrict__ A,
    const unsigned short* __restrict__ Bt,
    const float* __restrict__ bias,
    unsigned short* __restrict__ q_out,
    unsigned short* __restrict__ k_out,
    unsigned short* __restrict__ v_out,
    float* __restrict__ f_out) {
  constexpr int NB2 = BN / 32;
  constexpr int NBL = BN / 64;
  __shared__ __align__(16) unsigned short As[2][128 * 32];
  __shared__ __align__(16) unsigned short Bs[2][BN * 32];

  const int tid = threadIdx.x;
  const int wid = tid >> 6, lane = tid & 63;
  const int l15 = lane & 15, g = lane >> 4;
  const int wm = wid >> 1, wn = wid & 1;
  const int n0 = blockIdx.x * BN, m0 = blockIdx.y * 128;

  f32x4 acc[4][NB2] = {};

  auto stage = [&](int k0, int bsel) {
#pragma unroll
    for (int i = 0; i < 2; ++i) {
      int t = tid + i * 256;
      int row = t >> 2, c8 = (t & 3) << 3;
      gload16(A + (size_t)(m0 + row) * 1024 + k0 + c8, &As[bsel][(i * 256 + wid * 64) * 8]);
    }
#pragma unroll
    for (int i = 0; i < NBL; ++i) {
      int t = tid + i * 256;
      int row = t >> 2, c8 = (t & 3) << 3;
      gload16(Bt + (size_t)(n0 + row) * 1024 + k0 + c8, &Bs[bsel][(i * 256 + wid * 64) * 8]);
    }
  };

  stage(0, 0);
  __syncthreads();
  for (int ks = 0; ks < 32; ++ks) {
    const int cur = ks & 1;
    if (ks + 1 < 32) stage((ks + 1) * 32, cur ^ 1);  // lands under MFMA (T3-lite)
    bf16x8 a[4], b[NB2];
#pragma unroll
    for (int mi = 0; mi < 4; ++mi)
      a[mi] = *reinterpret_cast<const bf16x8*>(&As[cur][(wm * 64 + mi * 16 + l15) * 32 + g * 8]);
#pragma unroll
    for (int ni = 0; ni < NB2; ++ni)
      b[ni] = *reinterpret_cast<const bf16x8*>(&Bs[cur][(wn * (BN / 2) + ni * 16 + l15) * 32 + g * 8]);
    __builtin_amdgcn_s_setprio(1);
#pragma unroll
    for (int mi = 0; mi < 4; ++mi)
#pragma unroll
      for (int ni = 0; ni < NB2; ++ni)
        acc[mi][ni] = __builtin_amdgcn_mfma_f32_16x16x32_bf16(a[mi], b[ni], acc[mi][ni], 0, 0, 0);
    __builtin_amdgcn_s_setprio(0);
    __syncthreads();
  }

  if (MODE == 0) {
    const int which = n0 >> 10;  // block-uniform: q | k | v
    unsigned short* dst = (which == 0) ? q_out : (which == 1) ? k_out : v_out;
    // fold softmax scale * log2(e) into Q so attn's exp2-space scores need no mul
    const float oscale = (which == 0) ? 0.125f * 1.44269504f : 1.0f;
#pragma unroll
    for (int ni = 0; ni < NB2; ++ni) {
      int col = n0 + wn * (BN / 2) + ni * 16 + l15;
      int c = col & 1023;
      int h = c >> 6, d = c & 63;
      float bv = bias[col];
#pragma unroll
      for (int mi = 0; mi < 4; ++mi) {
#pragma unroll
        for (int r = 0; r < 4; ++r) {
          int rowg = m0 + wm * 64 + mi * 16 + g * 4 + r;
          int bb = rowg >> 11, tt = rowg & 2047;
          dst[((bb * 16 + h) * 2048 + tt) * 64 + d] = f2bf((acc[mi][ni][r] + bv) * oscale);
        }
      }
    }
  } else {
#pragma unroll
    for (int ni = 0; ni < NB2; ++ni) {
      int col = n0 + wn * (BN / 2) + ni * 16 + l15;
      float bv = bias[col];
#pragma unroll
      for (int mi = 0; mi < 4; ++mi)
#pragma unroll
        for (int r = 0; r < 4; ++r) {
          int rowg = m0 + wm * 64 + mi * 16 + g * 4 + r;
          f_out[(size_t)rowg * 1024 + col] = acc[mi][ni][r] + bv;
        }
    }
  }
}

// ---------------- causal flash attention ----------------
// Q,K,V: [BH=32][T=2048][D=64] bf16 (Q pre-scaled by 0.125*log2e).
// O: [B*T=4096][C=1024] bf16. grid (16,32): q-tiles {pi, 31-pi} = 33 KV-tiles.
#define KS_SZ (64 * 64)
#define VT_SZ (64 * 72)

__device__ __forceinline__ void attn_stage_K(const unsigned short* __restrict__ Kb,
                                             int k0, unsigned short* KsBuf,
                                             int tid, int wid) {
#pragma unroll
  for (int i = 0; i < 2; ++i) {
    int t = tid + i * 256;
    int row = t >> 3;
    int cb = (t & 7) << 4;
    int src = cb ^ ((row & 7) << 4);  // pre-swizzled global source (rule 21)
    gload16((const char*)Kb + (size_t)(k0 + row) * 128 + src,
            (char*)KsBuf + (i * 256 + wid * 64) * 16);
  }
}

// V [2 rows kvL,kvL+1][8 d] -> Vt[d][kv] stride 72, via v_perm packing
__device__ __forceinline__ void write_vt(unsigned short* VtBuf, int kvL, int d8,
                                         uint4 v0, uint4 v1) {
  unsigned* base = reinterpret_cast<unsigned*>(&VtBuf[(size_t)d8 * 72 + kvL]);
  unsigned lo, hi;
  lo = __builtin_amdgcn_perm(v1.x, v0.x, 0x05040100u);
  hi = __builtin_amdgcn_perm(v1.x, v0.x, 0x07060302u);
  base[0] = lo;   base[36] = hi;
  lo = __builtin_amdgcn_perm(v1.y, v0.y, 0x05040100u);
  hi = __builtin_amdgcn_perm(v1.y, v0.y, 0x07060302u);
  base[72] = lo;  base[108] = hi;
  lo = __builtin_amdgcn_perm(v1.z, v0.z, 0x05040100u);
  hi = __builtin_amdgcn_perm(v1.z, v0.z, 0x07060302u);
  base[144] = lo; base[180] = hi;
  lo = __builtin_amdgcn_perm(v1.w, v0.w, 0x05040100u);
  hi = __builtin_amdgcn_perm(v1.w, v0.w, 0x07060302u);
  base[216] = lo; base[252] = hi;
}

__device__ __forceinline__ void attn_run_qtile(
    const unsigned short* __restrict__ Qb,
    const unsigned short* __restrict__ Kb,
    const unsigned short* __restrict__ Vb,
    unsigned short* __restrict__ O,
    int b, int h, int q0, int nt,
    unsigned short* Ks, unsigned short* Vt, unsigned short* Ps,
    int tid, int wid, int l15, int g) {
  bf16x8 qf[2];
  {
    const unsigned short* qrow_p = Qb + (size_t)(q0 + wid * 16 + l15) * 64;
    qf[0] = *reinterpret_cast<const bf16x8*>(qrow_p + g * 8);
    qf[1] = *reinterpret_cast<const bf16x8*>(qrow_p + 32 + g * 8);
  }

  float m_run = -1e30f;
  float l_run = 0.0f;  // per-lane partial (16 of the row's 64 P values)
  f32x4 ot[4] = {};
  const int qg = q0 + wid * 16 + l15;
  const int kvL = (tid & 31) * 2, d8 = (tid >> 5) * 8;
  const int qrow = wid * 16 + l15;

  attn_stage_K(Kb, 0, Ks, tid, wid);
  {
    const uint4* vp = reinterpret_cast<const uint4*>(Vb + (size_t)kvL * 64 + d8);
    write_vt(Vt, kvL, d8, vp[0], vp[8]);  // +64 shorts = +8 uint4
  }
  __syncthreads();

  for (int t = 0; t < nt; ++t) {
    const unsigned short* KsC = Ks + (t & 1) * KS_SZ;
    const unsigned short* VtC = Vt + (t & 1) * VT_SZ;
    uint4 va, vb;
    const bool pf = (t + 1 < nt);
    if (pf) {
      attn_stage_K(Kb, (t + 1) << 6, Ks + ((t + 1) & 1) * KS_SZ, tid, wid);
      const uint4* vp = reinterpret_cast<const uint4*>(
          Vb + (size_t)(((t + 1) << 6) + kvL) * 64 + d8);
      va = vp[0];
      vb = vp[8];
    }

    // S^T = K · Q^T (Q pre-scaled, exp2 space)
    f32x4 s[4] = {};
    __builtin_amdgcn_s_setprio(1);
#pragma unroll
    for (int kk = 0; kk < 2; ++kk)
#pragma unroll
      for (int mi = 0; mi < 4; ++mi) {
        int row = mi * 16 + l15;
        int cb = (kk * 64 + g * 16) ^ ((row & 7) << 4);
        bf16x8 kf = *reinterpret_cast<const bf16x8*>((const char*)KsC + row * 128 + cb);
        s[mi] = __builtin_amdgcn_mfma_f32_16x16x32_bf16(kf, qf[kk], s[mi], 0, 0, 0);
      }
    __builtin_amdgcn_s_setprio(0);

    // causal mask on diagonal tile only
    if (t == nt - 1) {
      const int k0 = t << 6;
#pragma unroll
      for (int mi = 0; mi < 4; ++mi)
#pragma unroll
        for (int r = 0; r < 4; ++r) {
          int kvg = k0 + mi * 16 + g * 4 + r;
          s[mi][r] = (kvg <= qg) ? s[mi][r] : -1e30f;
        }
    }

    // per-lane partial max (no shfl on common path; any-lane-overflow vote is sound)
    float pmax = -1e30f;
#pragma unroll
    for (int mi = 0; mi < 4; ++mi)
#pragma unroll
      for (int r = 0; r < 4; ++r) pmax = fmaxf(pmax, s[mi][r]);

    if (!__all(pmax <= m_run + 8.0f)) {  // defer-max (T13), rare path
      float tmax = fmaxf(pmax, __shfl_xor(pmax, 16));
      tmax = fmaxf(tmax, __shfl_xor(tmax, 32));
      float m_new = fmaxf(m_run, tmax);
      float corr = __builtin_amdgcn_exp2f(m_run - m_new);
      l_run *= corr;
#pragma unroll
      for (int mi = 0; mi < 4; ++mi)
#pragma unroll
        for (int r = 0; r < 4; ++r) ot[mi][r] *= corr;
      m_run = m_new;
    }

    // P = exp2(s - m), pack via v_cvt_pk_bf16_f32, b64 LDS writes
    float tsum = 0.f;
#pragma unroll
    for (int mi = 0; mi < 4; ++mi) {
      float p0 = __builtin_amdgcn_exp2f(s[mi][0] - m_run);
      float p1 = __builtin_amdgcn_exp2f(s[mi][1] - m_run);
      float p2 = __builtin_amdgcn_exp2f(s[mi][2] - m_run);
      float p3 = __builtin_amdgcn_exp2f(s[mi][3] - m_run);
      tsum += (p0 + p1) + (p2 + p3);
      uint2 pk;
      pk.x = cvt_pk_bf16(p0, p1);
      pk.y = cvt_pk_bf16(p2, p3);
      *reinterpret_cast<uint2*>((char*)Ps + qrow * 144 + mi * 32 + g * 8) = pk;
    }
    l_run += tsum;  // stays per-lane partial; reduced once at epilogue

    // O^T += V^T · P^T
    __builtin_amdgcn_s_setprio(1);
#pragma unroll
    for (int kk = 0; kk < 2; ++kk) {
      bf16x8 pfr = *reinterpret_cast<const bf16x8*>(Ps + qrow * 72 + kk * 32 + g * 8);
#pragma unroll
      for (int mi = 0; mi < 4; ++mi) {
        bf16x8 vf = *reinterpret_cast<const bf16x8*>(VtC + (mi * 16 + l15) * 72 + kk * 32 + g * 8);
        ot[mi] = __builtin_amdgcn_mfma_f32_16x16x32_bf16(vf, pfr, ot[mi], 0, 0, 0);
      }
    }
    __builtin_amdgcn_s_setprio(0);

    if (pf) write_vt(Vt + ((t + 1) & 1) * VT_SZ, kvL, d8, va, vb);
    __syncthreads();
  }

  // reduce per-lane l partials (once per q-tile)
  float l_tot = l_run + __shfl_xor(l_run, 16);
  l_tot += __shfl_xor(l_tot, 32);
  float inv_l = 1.0f / l_tot;

  // epilogue: O^T -> LDS (reuse Ks, swizzled) -> coalesced stores
#pragma unroll
  for (int mi = 0; mi < 4; ++mi) {
    uint2 pk;
    pk.x = cvt_pk_bf16(ot[mi][0] * inv_l, ot[mi][1] * inv_l);
    pk.y = cvt_pk_bf16(ot[mi][2] * inv_l, ot[mi][3] * inv_l);
    int b0 = (mi * 32 + g * 8) ^ ((qrow & 7) << 4);
    *reinterpret_cast<uint2*>((char*)Ks + qrow * 128 + b0) = pk;
  }
  __syncthreads();
#pragma unroll
  for (int i = 0; i < 2; ++i) {
    int t = tid + i * 256;
    int row = t >> 3;
    int cb = (t & 7) << 4;
    int sw = cb ^ ((row & 7) << 4);
    bf16x8 vv = *reinterpret_cast<const bf16x8*>((const char*)Ks + row * 128 + sw);
    *reinterpret_cast<bf16x8*>(O + ((size_t)(b * 2048 + q0 + row)) * 1024 + h * 64 + (cb >> 1)) = vv;
  }
  __syncthreads();
}

__global__ __launch_bounds__(256, 2) void attn_fwd(
    const unsigned short* __restrict__ Q,
    const unsigned short* __restrict__ K,
    const unsigned short* __restrict__ V,
    unsigned short* __restrict__ O) {
  __shared__ __align__(16) unsigned short Ks[2 * KS_SZ];  // 16 KB, XOR-swizzled
  __shared__ __align__(16) unsigned short Vt[2 * VT_SZ];  // 18 KB, V^T stride 72
  __shared__ __align__(16) unsigned short Ps[64 * 72];    // 9 KB

  const int tid = threadIdx.x;
  const int wid = tid >> 6;
  const int l15 = tid & 15;
  const int g = (tid & 63) >> 4;

  // bijective XCD swizzle (T1): all 16 q-tile blocks of one bh on one XCD
  int lin = blockIdx.x + (blockIdx.y << 4);
  int w = ((lin & 7) << 6) + (lin >> 3);
  const int pi = w & 15, bh = w >> 4;
  const int b = bh >> 4, h = bh & 15;

  const unsigned short* Qb = Q + (size_t)bh * 2048 * 64;
  const unsigned short* Kb = K + (size_t)bh * 2048 * 64;
  const unsigned short* Vb = V + (size_t)bh * 2048 * 64;

  attn_run_qtile(Qb, Kb, Vb, O, b, h, pi << 6, pi + 1, Ks, Vt, Ps, tid, wid, l15, g);
  attn_run_qtile(Qb, Kb, Vb, O, b, h, (31 - pi) << 6, 32 - pi, Ks, Vt, Ps, tid, wid, l15, g);
}

// ---------------- launch ----------------
extern "C" void kernel_launch(void* const* d_in, const int* in_sizes, int n_in,
                              void* d_out, int out_size, void* d_ws, size_t ws_size,
                              hipStream_t stream) {
  const float* x = (const float*)d_in[0];
  const float* w_qkv = (const float*)d_in[1];
  const float* b_qkv = (const float*)d_in[2];
  const float* w_out = (const float*)d_in[3];
  const float* b_out = (const float*)d_in[4];
  float* out = (float*)d_out;
  char* ws = (char*)d_ws;

  unsigned short* xb    = (unsigned short*)d_out;            // dead before GEMM2 writes
  unsigned short* wqkvT = (unsigned short*)(ws);             //  6 MB
  unsigned short* woT   = (unsigned short*)(ws + 6291456);   //  2 MB
  unsigned short* q_buf = (unsigned short*)(ws + 8388608);   //  8 MB
  unsigned short* k_buf = (unsigned short*)(ws + 16777216);  //  8 MB
  unsigned short* v_buf = (unsigned short*)(ws + 25165824);  //  8 MB
  unsigned short* aout  = (unsigned short*)(ws + 33554432);  //  8 MB -> 40 MB total

  prep_kernel<<<dim3(8192), dim3(256), 0, stream>>>(x, w_qkv, w_out, xb, wqkvT, woT);

  gemm_bf16<0, 128><<<dim3(24, 32), dim3(256), 0, stream>>>(
      xb, wqkvT, b_qkv, q_buf, k_buf, v_buf, nullptr);

  attn_fwd<<<dim3(16, 32), dim3(256), 0, stream>>>(q_buf, k_buf, v_buf, aout);

  gemm_bf16<1, 64><<<dim3(16, 32), dim3(256), 0, stream>>>(
      aout, woT, b_out, nullptr, nullptr, nullptr, out);
}